// Round 1
// baseline (122.329 us; speedup 1.0000x reference)
//
#include <hip/hip_runtime.h>
#include <hip/hip_bf16.h>

// RoI crop: out[n,b,i,j,c] = features[b, x1(n)+i, y1(n)+j, c]
// features: [B=8, 64, 64, C=256] f32 ; boxes: [N=1000, 4] i32 (x1,y1,x2,y2)
// out: [N, B, 7, 7, C] f32
//
// Memory-bound (401 MB streaming write, 33.5 MB read footprint -> L2/L3).
// One block per box, 512 threads = 8 waves. Each wave copies one 256-float
// row per iteration as 64 lanes x float4 (16 B/lane, fully coalesced).

#define ANCHOR 7
#define FS     64
#define NBOX   1000
#define BB     8
#define CC     256
#define ROWS   (BB * ANCHOR * ANCHOR)   // 392 rows per box
#define C4     (CC / 4)                 // 64 float4 per row

__global__ __launch_bounds__(512) void roi_crop_kernel(
    const float4* __restrict__ fin,     // features as float4
    const int*    __restrict__ boxes,   // [N,4]
    float4*       __restrict__ fout)    // out as float4
{
    const int n    = blockIdx.x;        // box index
    const int lane = threadIdx.x & 63;
    const int wave = threadIdx.x >> 6;  // 0..7

    int x1 = boxes[n * 4 + 0];
    int y1 = boxes[n * 4 + 1];
    // clamp start (edge-snap equivalent for fixed-size boxes)
    x1 = min(max(x1, 0), FS - ANCHOR);
    y1 = min(max(y1, 0), FS - ANCHOR);

    const int obase = n * (ROWS * C4);  // float4 index; max ~25.06M < 2^31

    #pragma unroll 1
    for (int r = wave; r < ROWS; r += 8) {
        // wave-uniform decomposition: r -> (b, i, j)
        int b  = r / 49;
        int ij = r - b * 49;
        int i  = ij / 7;
        int j  = ij - i * 7;
        int src = ((b * FS + (x1 + i)) * FS + (y1 + j)) * C4 + lane;
        fout[obase + r * C4 + lane] = fin[src];
    }
}

extern "C" void kernel_launch(void* const* d_in, const int* in_sizes, int n_in,
                              void* d_out, int out_size, void* d_ws, size_t ws_size,
                              hipStream_t stream) {
    const float4* fin  = (const float4*)d_in[0];
    const int*   boxes = (const int*)d_in[1];
    float4*      fout  = (float4*)d_out;

    roi_crop_kernel<<<NBOX, 512, 0, stream>>>(fin, boxes, fout);
}

// Round 3
// 108.971 us; speedup vs baseline: 1.1226x; 1.1226x over previous
//
#include <hip/hip_runtime.h>
#include <hip/hip_bf16.h>

// RoI crop: out[n,b,i,j,c] = features[b, x1(n)+i, y1(n)+j, c]
// features: [B=8, 64, 64, C=256] f32 ; boxes: [N=1000, 4] i32 (x1,y1,x2,y2)
// out: [N, B, 7, 7, C] f32  (401 MB streaming write -> write-BW bound)
//
// R2: same as R1 but with clang ext_vector_type so nontemporal builtins
// compile (HIP_vector_type float4 is a struct and is rejected).
//  - 8000 waves, exactly 49 rows (one b-slice, 7x7) per wave.
//  - 7 loads in flight per wave (unroll j), then 7 nontemporal stores
//    (keep the 33.5 MB feature map L2-resident; output is write-once).

#define ANCHOR 7
#define FS     64
#define NBOX   1000
#define BB     8
#define CC     256
#define C4     (CC / 4)                 // 64 f32x4 per row
#define ROWS   (BB * ANCHOR * ANCHOR)   // 392 rows per box

typedef float f32x4 __attribute__((ext_vector_type(4)));

__global__ __launch_bounds__(256) void roi_crop_kernel(
    const f32x4* __restrict__ fin,      // features as f32x4
    const int*   __restrict__ boxes,    // [N,4]
    f32x4*       __restrict__ fout)     // out as f32x4
{
    const int lane = threadIdx.x & 63;
    const int wave = threadIdx.x >> 6;          // 0..3
    const int w    = blockIdx.x * 4 + wave;     // global wave id, 0..7999
    const int n    = w >> 3;                    // box index
    const int b    = w & 7;                     // batch slice

    int x1 = boxes[n * 4 + 0];
    int y1 = boxes[n * 4 + 1];
    x1 = min(max(x1, 0), FS - ANCHOR);
    y1 = min(max(y1, 0), FS - ANCHOR);

    const f32x4* __restrict__ src = fin + ((b * FS + x1) * FS + y1) * C4 + lane;
    f32x4* __restrict__ dst = fout + n * (ROWS * C4) + b * (ANCHOR * ANCHOR * C4) + lane;

    #pragma unroll
    for (int i = 0; i < ANCHOR; ++i) {
        f32x4 v[ANCHOR];
        #pragma unroll
        for (int j = 0; j < ANCHOR; ++j)
            v[j] = src[(i * FS + j) * C4];      // 7 loads issued back-to-back
        #pragma unroll
        for (int j = 0; j < ANCHOR; ++j)
            __builtin_nontemporal_store(v[j], &dst[(i * ANCHOR + j) * C4]);
    }
}

extern "C" void kernel_launch(void* const* d_in, const int* in_sizes, int n_in,
                              void* d_out, int out_size, void* d_ws, size_t ws_size,
                              hipStream_t stream) {
    const f32x4* fin  = (const f32x4*)d_in[0];
    const int*  boxes = (const int*)d_in[1];
    f32x4*      fout  = (f32x4*)d_out;

    roi_crop_kernel<<<NBOX * BB / 4, 256, 0, stream>>>(fin, boxes, fout);
}

// Round 4
// 82.347 us; speedup vs baseline: 1.4855x; 1.3233x over previous
//
#include <hip/hip_runtime.h>
#include <hip/hip_bf16.h>

// RoI crop: out[n,b,i,j,c] = features[b, x1(n)+i, y1(n)+j, c]
// features: [B=8, 64, 64, C=256] f32 ; boxes: [N=1000, 4] i32 (x1,y1,x2,y2)
// out: [N, B, 7, 7, C] f32  (401 MB streaming write)
//
// R3: XCD-pinned batch slices. One b-slice of the feature map = 4 MB =
// exactly one XCD's L2. Blocks round-robin to XCDs by blockIdx%8, so
// block x takes b = x&7 -> XCD k only reads slice b=k -> reads become
// L2 hits after 4 MB compulsory misses. Memory-side traffic drops from
// ~800 MB (read+write) to ~435 MB; write stream becomes the only limiter.
//  - 2000 blocks x 4 waves; wave handles one (n,b): 49 rows of 1 KB.
//  - 7 loads in flight, then 7 nontemporal stores (bypass L2 on writes).

#define ANCHOR 7
#define FS     64
#define NBOX   1000
#define BB     8
#define CC     256
#define C4     (CC / 4)                 // 64 f32x4 per row
#define ROWS   (BB * ANCHOR * ANCHOR)   // 392 rows per box

typedef float f32x4 __attribute__((ext_vector_type(4)));

__global__ __launch_bounds__(256) void roi_crop_kernel(
    const f32x4* __restrict__ fin,      // features as f32x4
    const int*   __restrict__ boxes,    // [N,4]
    f32x4*       __restrict__ fout)     // out as f32x4
{
    const int lane = threadIdx.x & 63;
    const int wave = threadIdx.x >> 6;          // 0..3
    const int x    = blockIdx.x;                // 0..1999
    const int b    = x & 7;                     // batch slice == XCD id
    const int n    = (x >> 3) * 4 + wave;       // box index, 0..999

    int x1 = boxes[n * 4 + 0];
    int y1 = boxes[n * 4 + 1];
    x1 = min(max(x1, 0), FS - ANCHOR);
    y1 = min(max(y1, 0), FS - ANCHOR);

    const f32x4* __restrict__ src = fin + ((b * FS + x1) * FS + y1) * C4 + lane;
    f32x4* __restrict__ dst = fout + n * (ROWS * C4) + b * (ANCHOR * ANCHOR * C4) + lane;

    #pragma unroll
    for (int i = 0; i < ANCHOR; ++i) {
        f32x4 v[ANCHOR];
        #pragma unroll
        for (int j = 0; j < ANCHOR; ++j)
            v[j] = src[(i * FS + j) * C4];      // 7 loads issued back-to-back
        #pragma unroll
        for (int j = 0; j < ANCHOR; ++j)
            __builtin_nontemporal_store(v[j], &dst[(i * ANCHOR + j) * C4]);
    }
}

extern "C" void kernel_launch(void* const* d_in, const int* in_sizes, int n_in,
                              void* d_out, int out_size, void* d_ws, size_t ws_size,
                              hipStream_t stream) {
    const f32x4* fin  = (const f32x4*)d_in[0];
    const int*  boxes = (const int*)d_in[1];
    f32x4*      fout  = (f32x4*)d_out;

    roi_crop_kernel<<<NBOX * BB / 4, 256, 0, stream>>>(fin, boxes, fout);
}